// Round 11
// baseline (535.032 us; speedup 1.0000x reference)
//
#include <hip/hip_runtime.h>
#include <math.h>

#define TSEQ 512
#define FDIM 64
#define HDIM 128
#define NB   512

typedef _Float16 f16x8 __attribute__((ext_vector_type(8)));
typedef __fp16  fp16x2 __attribute__((ext_vector_type(2)));
typedef __attribute__((ext_vector_type(4))) float f32x4;

#define H_ROW 136                 // halves per batch row (+8 pad)
#define H_BUF (16 * H_ROW)

__device__ __forceinline__ float fast_sig(float x) {
    return __builtin_amdgcn_rcpf(1.0f + __expf(-x));
}
__device__ __forceinline__ float fast_tanh(float x) {
    return 1.0f - 2.0f * __builtin_amdgcn_rcpf(1.0f + __expf(2.0f * x));
}
__device__ __forceinline__ f32x4 mfma16f(f16x8 a, f16x8 b, f32x4 c) {
    return __builtin_amdgcn_mfma_f32_16x16x32_f16(a, b, c, 0, 0, 0);
}

union PU { fp16x2 h2[4]; f16x8 v; };
union GU { uint2 u; _Float16 h[4]; };

__device__ __forceinline__ f16x8 pack_f16(float4 a, float4 b) {
    PU u;
    u.h2[0] = __builtin_amdgcn_cvt_pkrtz(a.x, a.y);
    u.h2[1] = __builtin_amdgcn_cvt_pkrtz(a.z, a.w);
    u.h2[2] = __builtin_amdgcn_cvt_pkrtz(b.x, b.y);
    u.h2[3] = __builtin_amdgcn_cvt_pkrtz(b.z, b.w);
    return u.v;
}

// Raw barrier: drain LDS only. Global loads/stores (vmcnt) stay in flight.
__device__ __forceinline__ void wg_barrier() {
    __builtin_amdgcn_sched_barrier(0);
    asm volatile("s_waitcnt lgkmcnt(0)" ::: "memory");
    __builtin_amdgcn_s_barrier();
    asm volatile("" ::: "memory");
    __builtin_amdgcn_sched_barrier(0);
}

// ---------------- pre-GEMM: gi (fp16, biases folded), COALESCED layout ----
// gi viewed as uint2[TSEQ][96][NB]: chunk c = kd*32 + w*4 + g4 covers gate
// rows 4c..4c+3; innermost index = batch -> consecutive lanes are 8B apart.
__global__ __launch_bounds__(512)
void gi_gemm16(const float* __restrict__ x,
               const float* __restrict__ W_ih,
               const float* __restrict__ b_ih,
               const float* __restrict__ b_hh,
               uint2* __restrict__ gi)
{
    const int tid  = threadIdx.x;
    const int w    = tid >> 6;
    const int lane = tid & 63;
    const int g4   = lane >> 4;
    const int bcol = lane & 15;
    const int b0   = blockIdx.x * 16;
    const int t0   = blockIdx.y * 16;

    f16x8 WihF[3][2];
    #pragma unroll
    for (int kd = 0; kd < 3; ++kd) {
        const int g = kd * 128 + w * 16 + bcol;
        #pragma unroll
        for (int kt = 0; kt < 2; ++kt) {
            const float* pw = W_ih + g * FDIM + kt * 32 + g4 * 8;
            f16x8 v;
            #pragma unroll
            for (int e = 0; e < 8; ++e) v[e] = (_Float16)pw[e];
            WihF[kd][kt] = v;
        }
    }
    f32x4 biasR, biasZ, biasN;
    #pragma unroll
    for (int i = 0; i < 4; ++i) {
        const int gr = w * 16 + g4 * 4 + i;
        biasR[i] = b_ih[gr]       + b_hh[gr];
        biasZ[i] = b_ih[128 + gr] + b_hh[128 + gr];
        biasN[i] = b_ih[256 + gr];
    }

    for (int tt = 0; tt < 16; ++tt) {
        const int t = t0 + tt;
        const float* xp = x + ((size_t)(b0 + bcol) * TSEQ + t) * FDIM;
        float4 a0 = *(const float4*)(xp + g4 * 8);
        float4 a1 = *(const float4*)(xp + g4 * 8 + 4);
        float4 a2 = *(const float4*)(xp + 32 + g4 * 8);
        float4 a3 = *(const float4*)(xp + 32 + g4 * 8 + 4);
        f16x8 xf0 = pack_f16(a0, a1);
        f16x8 xf1 = pack_f16(a2, a3);

        f32x4 c0 = biasR, c1 = biasZ, c2 = biasN;
        c0 = mfma16f(WihF[0][0], xf0, c0);
        c0 = mfma16f(WihF[0][1], xf1, c0);
        c1 = mfma16f(WihF[1][0], xf0, c1);
        c1 = mfma16f(WihF[1][1], xf1, c1);
        c2 = mfma16f(WihF[2][0], xf0, c2);
        c2 = mfma16f(WihF[2][1], xf1, c2);

        GU g0, g1, g2;
        #pragma unroll
        for (int i = 0; i < 4; ++i) {
            g0.h[i] = (_Float16)c0[i];   // RNE
            g1.h[i] = (_Float16)c1[i];
            g2.h[i] = (_Float16)c2[i];
        }
        const size_t base = ((size_t)t * 96 + w * 4 + g4) * NB + (b0 + bcol);
        gi[base]               = g0.u;
        gi[base + 32 * NB]     = g1.u;
        gi[base + 64 * NB]     = g2.u;
    }
}

// ---------------- out finalize: out[b][t] = tanh(W_out·h_t + b_out) -------
// hh viewed as uint2[TSEQ][32][NB]; block = t, thread = b (coalesced reads).
__global__ __launch_bounds__(512)
void out_final(const uint2* __restrict__ hh,
               const float* __restrict__ W_out,
               const float* __restrict__ b_out,
               float* __restrict__ out)
{
    const int t = blockIdx.x;
    const int b = threadIdx.x;
    __shared__ float wsm[128];
    if (b < 128) wsm[b] = W_out[b];
    __syncthreads();

    float acc = b_out[0];
    const uint2* p = hh + (size_t)t * 32 * NB + b;
    #pragma unroll
    for (int c = 0; c < 32; ++c) {
        GU g; g.u = p[(size_t)c * NB];
        acc = fmaf(wsm[4 * c],     (float)g.h[0], acc);
        acc = fmaf(wsm[4 * c + 1], (float)g.h[1], acc);
        acc = fmaf(wsm[4 * c + 2], (float)g.h[2], acc);
        acc = fmaf(wsm[4 * c + 3], (float)g.h[3], acc);
    }
    out[(size_t)b * TSEQ + t] = fast_tanh(acc);
}

// ---------------- recurrence ----------------------------------------------
// 32 blocks x 16 batches, 512 threads = 8 waves. fp16 single-term, f32 acc.
// USE_GI: gi coalesced [t][96][NB] uint2; 4-slot prefetch 4 steps ahead.
// STORE_H: no psum/out in-loop; h16 stored to hh [t][32][NB] (fire-and-
// forget vmcnt store, not drained by the lgkm-only barrier).
template<bool USE_GI, bool STORE_H>
__global__ __launch_bounds__(512, 2)
void gru_f16(const float* __restrict__ x,
             const float* __restrict__ W_ih,
             const float* __restrict__ W_hh,
             const float* __restrict__ b_ih,
             const float* __restrict__ b_hh,
             const float* __restrict__ W_out,
             const float* __restrict__ b_out,
             const uint2* __restrict__ gi,
             uint2* __restrict__ hh,
             float* __restrict__ out)
{
    const int tid  = threadIdx.x;
    const int wid  = tid >> 6;        // 0..7
    const int lane = tid & 63;
    const int g4   = lane >> 4;
    const int bcol = lane & 15;
    const int b0   = blockIdx.x * 16;

    __shared__ __align__(16) _Float16 h_s[3][16][H_ROW];
    __shared__ __align__(16) float ps_s[3][16][12];

    f16x8 WhhF[3][4];
    f16x8 WihF[3][2];
    #pragma unroll
    for (int kd = 0; kd < 3; ++kd) {
        const int g = kd * 128 + wid * 16 + bcol;
        #pragma unroll
        for (int kt = 0; kt < 4; ++kt) {
            const float* pw = W_hh + g * HDIM + kt * 32 + g4 * 8;
            f16x8 v;
            #pragma unroll
            for (int e = 0; e < 8; ++e) v[e] = (_Float16)pw[e];
            WhhF[kd][kt] = v;
        }
        if constexpr (!USE_GI) {
            #pragma unroll
            for (int kt = 0; kt < 2; ++kt) {
                const float* pw = W_ih + g * FDIM + kt * 32 + g4 * 8;
                f16x8 v;
                #pragma unroll
                for (int e = 0; e < 8; ++e) v[e] = (_Float16)pw[e];
                WihF[kd][kt] = v;
            }
        }
    }

    f32x4 biasR, biasZ, biasNI, biasNH;
    float wout_r[4], h_old[4];
    #pragma unroll
    for (int i = 0; i < 4; ++i) {
        const int gr = wid * 16 + g4 * 4 + i;
        if constexpr (!USE_GI) {
            biasR[i]  = b_ih[gr]       + b_hh[gr];
            biasZ[i]  = b_ih[128 + gr] + b_hh[128 + gr];
            biasNI[i] = b_ih[256 + gr];
        }
        biasNH[i] = b_hh[256 + gr];
        if constexpr (!STORE_H) wout_r[i] = W_out[gr];
        h_old[i]  = 0.0f;
    }
    const float bout = b_out[0];

    {   // zero h buffer 0
        unsigned* hp = (unsigned*)&h_s[0][0][0];
        for (int i = tid; i < H_BUF / 2; i += 512) hp[i] = 0u;
    }

    // ---- input pipelines ----
    const float* xb = x + (size_t)(b0 + bcol) * TSEQ * FDIM;
    float4 sA0, sA1, sA2, sA3, sB0, sB1, sB2, sB3;
    f16x8 xf0, xf1;
    GU r0s, z0s, n0s, r1s, z1s, n1s, r2s, z2s, n2s, r3s, z3s, n3s;
    const uint2* gB = nullptr;

    if constexpr (USE_GI) {
        // chunk base for this lane (kd=0): step stride 96*NB, kd stride 32*NB
        gB = gi + ((size_t)wid * 4 + g4) * NB + (b0 + bcol);
        r0s.u = gB[0];                 z0s.u = gB[32 * NB];
        n0s.u = gB[64 * NB];
        r1s.u = gB[(size_t)1 * 96 * NB];          z1s.u = gB[(size_t)1 * 96 * NB + 32 * NB];
        n1s.u = gB[(size_t)1 * 96 * NB + 64 * NB];
        r2s.u = gB[(size_t)2 * 96 * NB];          z2s.u = gB[(size_t)2 * 96 * NB + 32 * NB];
        n2s.u = gB[(size_t)2 * 96 * NB + 64 * NB];
        r3s.u = gB[(size_t)3 * 96 * NB];          z3s.u = gB[(size_t)3 * 96 * NB + 32 * NB];
        n3s.u = gB[(size_t)3 * 96 * NB + 64 * NB];
    } else {
        sA0 = *(const float4*)(xb + g4 * 8);
        sA1 = *(const float4*)(xb + g4 * 8 + 4);
        sA2 = *(const float4*)(xb + 32 + g4 * 8);
        sA3 = *(const float4*)(xb + 32 + g4 * 8 + 4);
        const float* xp1 = xb + FDIM;
        sB0 = *(const float4*)(xp1 + g4 * 8);
        sB1 = *(const float4*)(xp1 + g4 * 8 + 4);
        sB2 = *(const float4*)(xp1 + 32 + g4 * 8);
        sB3 = *(const float4*)(xp1 + 32 + g4 * 8 + 4);
        xf0 = pack_f16(sA0, sA1);
        xf1 = pack_f16(sA2, sA3);
    }

    __syncthreads();   // prologue barrier

    const bool outw = (!STORE_H) && (wid == 0) && (lane < 16);
    float* outp = out + (size_t)(b0 + lane) * TSEQ;
    float o0 = 0.f, o1 = 0.f, o2 = 0.f, o3 = 0.f;
    int rb = 0, wb = 1;

// consume slot (cvt to f32 accs), then refill slot with gi(s+4) if in range
#define GI_STEP(RS, ZS, NS)                                                 \
    a0a = (f32x4){(float)RS.h[0], (float)RS.h[1],                           \
                  (float)RS.h[2], (float)RS.h[3]};                          \
    a1  = (f32x4){(float)ZS.h[0], (float)ZS.h[1],                           \
                  (float)ZS.h[2], (float)ZS.h[3]};                          \
    a2  = (f32x4){(float)NS.h[0], (float)NS.h[1],                           \
                  (float)NS.h[2], (float)NS.h[3]};                          \
    if (s + 4 < TSEQ) {                                                     \
        const size_t gof = (size_t)(s + 4) * 96 * NB;                       \
        RS.u = gB[gof];                                                     \
        ZS.u = gB[gof + 32 * NB];                                           \
        NS.u = gB[gof + 64 * NB];                                           \
    }

    for (int t = 0; t < TSEQ; t += 4) {
        #pragma unroll
        for (int u = 0; u < 4; ++u) {
            const int s = t + u;

            if (outw && s > 0) {
                f32x4 q0 = *(const f32x4*)&ps_s[rb][lane][0];
                f32x4 q1 = *(const f32x4*)&ps_s[rb][lane][4];
                float sm = (q0[0] + q0[1]) + (q0[2] + q0[3])
                         + (q1[0] + q1[1]) + (q1[2] + q1[3]);
                float val = fast_tanh(sm + bout);
                if (u == 0) {
                    o3 = val;
                    *(float4*)(outp + (t - 4)) = make_float4(o0, o1, o2, o3);
                } else if (u == 1) o0 = val;
                else if (u == 2) o1 = val;
                else o2 = val;
            }

            f32x4 a0, a1, a2, a3;

            if constexpr (USE_GI) {
                f16x8 bh0 = *(const f16x8*)&h_s[rb][bcol][0 * 32 + g4 * 8];
                f16x8 bh1 = *(const f16x8*)&h_s[rb][bcol][1 * 32 + g4 * 8];
                f16x8 bh2 = *(const f16x8*)&h_s[rb][bcol][2 * 32 + g4 * 8];
                f16x8 bh3 = *(const f16x8*)&h_s[rb][bcol][3 * 32 + g4 * 8];

                f32x4 a0a;
                if (u == 0)      { GI_STEP(r0s, z0s, n0s) }
                else if (u == 1) { GI_STEP(r1s, z1s, n1s) }
                else if (u == 2) { GI_STEP(r2s, z2s, n2s) }
                else             { GI_STEP(r3s, z3s, n3s) }

                f32x4 a0b = {0.f, 0.f, 0.f, 0.f};
                f32x4 a3a = biasNH, a3b = {0.f, 0.f, 0.f, 0.f};
                a0a = mfma16f(WhhF[0][0], bh0, a0a);
                a3a = mfma16f(WhhF[2][0], bh0, a3a);
                a1  = mfma16f(WhhF[1][0], bh0, a1);
                a0b = mfma16f(WhhF[0][2], bh2, a0b);
                a3b = mfma16f(WhhF[2][2], bh2, a3b);
                a1  = mfma16f(WhhF[1][1], bh1, a1);
                a0a = mfma16f(WhhF[0][1], bh1, a0a);
                a3a = mfma16f(WhhF[2][1], bh1, a3a);
                a1  = mfma16f(WhhF[1][2], bh2, a1);
                a0b = mfma16f(WhhF[0][3], bh3, a0b);
                a3b = mfma16f(WhhF[2][3], bh3, a3b);
                a1  = mfma16f(WhhF[1][3], bh3, a1);

                a0 = a0a + a0b;
                a3 = a3a + a3b;
            } else {
                {
                    const int tl = (s + 2 < TSEQ) ? (s + 2) : (TSEQ - 1);
                    const float* xp = xb + (size_t)tl * FDIM;
                    if ((u & 1) == 0) {
                        sA0 = *(const float4*)(xp + g4 * 8);
                        sA1 = *(const float4*)(xp + g4 * 8 + 4);
                        sA2 = *(const float4*)(xp + 32 + g4 * 8);
                        sA3 = *(const float4*)(xp + 32 + g4 * 8 + 4);
                    } else {
                        sB0 = *(const float4*)(xp + g4 * 8);
                        sB1 = *(const float4*)(xp + g4 * 8 + 4);
                        sB2 = *(const float4*)(xp + 32 + g4 * 8);
                        sB3 = *(const float4*)(xp + 32 + g4 * 8 + 4);
                    }
                }
                f16x8 bh0 = *(const f16x8*)&h_s[rb][bcol][0 * 32 + g4 * 8];
                f16x8 bh1 = *(const f16x8*)&h_s[rb][bcol][1 * 32 + g4 * 8];
                f16x8 bh2 = *(const f16x8*)&h_s[rb][bcol][2 * 32 + g4 * 8];
                f16x8 bh3 = *(const f16x8*)&h_s[rb][bcol][3 * 32 + g4 * 8];

                f32x4 a0x = biasR, a1x = biasZ, a3l = biasNH;
                a2 = biasNI;
                f32x4 a0h = {0.f,0.f,0.f,0.f}, a1h = {0.f,0.f,0.f,0.f};

                a0x = mfma16f(WihF[0][0], xf0, a0x);
                a0x = mfma16f(WihF[0][1], xf1, a0x);
                a1x = mfma16f(WihF[1][0], xf0, a1x);
                a1x = mfma16f(WihF[1][1], xf1, a1x);
                a2  = mfma16f(WihF[2][0], xf0, a2);
                a2  = mfma16f(WihF[2][1], xf1, a2);

                a0h = mfma16f(WhhF[0][0], bh0, a0h);
                a1h = mfma16f(WhhF[1][0], bh0, a1h);
                a3l = mfma16f(WhhF[2][0], bh0, a3l);
                a0h = mfma16f(WhhF[0][1], bh1, a0h);
                a1h = mfma16f(WhhF[1][1], bh1, a1h);
                a3l = mfma16f(WhhF[2][1], bh1, a3l);
                a0h = mfma16f(WhhF[0][2], bh2, a0h);
                a1h = mfma16f(WhhF[1][2], bh2, a1h);
                a3l = mfma16f(WhhF[2][2], bh2, a3l);
                a0h = mfma16f(WhhF[0][3], bh3, a0h);
                a1h = mfma16f(WhhF[1][3], bh3, a1h);
                a3l = mfma16f(WhhF[2][3], bh3, a3l);

                a0 = a0x + a0h;
                a1 = a1x + a1h;
                a3 = a3l;
            }

            // ---- gates (in-register) ----
            float psum = 0.0f;
            _Float16 h16[4];
            #pragma unroll
            for (int i = 0; i < 4; ++i) {
                float r  = fast_sig(a0[i]);
                float z  = fast_sig(a1[i]);
                float n  = fast_tanh(a2[i] + r * a3[i]);
                float hn = n + z * (h_old[i] - n);
                h_old[i] = hn;
                h16[i]   = (_Float16)hn;   // RNE
                if constexpr (!STORE_H) psum = fmaf(wout_r[i], hn, psum);
            }

            union { _Float16 h[4]; uint2 u; } hu;
            hu.h[0] = h16[0]; hu.h[1] = h16[1];
            hu.h[2] = h16[2]; hu.h[3] = h16[3];
            *(uint2*)&h_s[wb][bcol][wid * 16 + g4 * 4] = hu.u;

            if constexpr (STORE_H) {
                hh[((size_t)s * 32 + wid * 4 + g4) * NB + (b0 + bcol)] = hu.u;
            } else {
                psum += __shfl_xor(psum, 16);
                psum += __shfl_xor(psum, 32);
                if (lane < 16) ps_s[wb][lane][wid] = psum;
            }

            if constexpr (!USE_GI) {
                if ((u & 1) == 0) {
                    xf0 = pack_f16(sB0, sB1);
                    xf1 = pack_f16(sB2, sB3);
                } else {
                    xf0 = pack_f16(sA0, sA1);
                    xf1 = pack_f16(sA2, sA3);
                }
            }

            wg_barrier();
            rb = wb; wb = (wb == 2) ? 0 : wb + 1;
        }
    }
#undef GI_STEP

    if (outw) {
        f32x4 q0 = *(const f32x4*)&ps_s[2][lane][0];
        f32x4 q1 = *(const f32x4*)&ps_s[2][lane][4];
        float sm = (q0[0] + q0[1]) + (q0[2] + q0[3])
                 + (q1[0] + q1[1]) + (q1[2] + q1[3]);
        o3 = fast_tanh(sm + bout);
        *(float4*)(outp + (TSEQ - 4)) = make_float4(o0, o1, o2, o3);
    }
}

extern "C" void kernel_launch(void* const* d_in, const int* in_sizes, int n_in,
                              void* d_out, int out_size, void* d_ws, size_t ws_size,
                              hipStream_t stream) {
    const float* x     = (const float*)d_in[0];
    const float* W_ih  = (const float*)d_in[1];
    const float* W_hh  = (const float*)d_in[2];
    const float* b_ih  = (const float*)d_in[3];
    const float* b_hh  = (const float*)d_in[4];
    const float* W_out = (const float*)d_in[5];
    const float* b_out = (const float*)d_in[6];
    float* out = (float*)d_out;

    const size_t gi_bytes = (size_t)TSEQ * NB * 384 * sizeof(_Float16); // 201.3 MB
    const size_t hh_bytes = (size_t)TSEQ * NB * HDIM * sizeof(_Float16); // 67.1 MB

    if (ws_size >= gi_bytes + hh_bytes) {
        uint2* gi = (uint2*)d_ws;
        uint2* hh = (uint2*)((char*)d_ws + gi_bytes);
        gi_gemm16<<<dim3(32, 32), 512, 0, stream>>>(x, W_ih, b_ih, b_hh, gi);
        gru_f16<true, true><<<32, 512, 0, stream>>>(x, W_ih, W_hh, b_ih, b_hh,
                                                    W_out, b_out, gi, hh, out);
        out_final<<<TSEQ, NB, 0, stream>>>(hh, W_out, b_out, out);
    } else if (ws_size >= gi_bytes) {
        uint2* gi = (uint2*)d_ws;
        gi_gemm16<<<dim3(32, 32), 512, 0, stream>>>(x, W_ih, b_ih, b_hh, gi);
        gru_f16<true, false><<<32, 512, 0, stream>>>(x, W_ih, W_hh, b_ih, b_hh,
                                                     W_out, b_out, gi, nullptr, out);
    } else {
        gru_f16<false, false><<<32, 512, 0, stream>>>(x, W_ih, W_hh, b_ih, b_hh,
                                                      W_out, b_out, nullptr, nullptr, out);
    }
}

// Round 12
// 364.532 us; speedup vs baseline: 1.4677x; 1.4677x over previous
//
#include <hip/hip_runtime.h>
#include <math.h>

#define TSEQ 512
#define FDIM 64
#define HDIM 128
#define NB   512

// prescales folded into weights/biases so activations use raw exp2
#define SR 1.4426950408889634f   // log2(e)   : r,z gates
#define SN 2.8853900817779268f   // 2*log2(e) : n gate

typedef _Float16 f16x8 __attribute__((ext_vector_type(8)));
typedef __fp16  fp16x2 __attribute__((ext_vector_type(2)));
typedef __attribute__((ext_vector_type(4))) float f32x4;

#define H_ROW 136                 // halves per batch row (+8 pad)
#define H_BUF (16 * H_ROW)

__device__ __forceinline__ float exp2_hw(float x) {
#if __has_builtin(__builtin_amdgcn_exp2f)
    return __builtin_amdgcn_exp2f(x);
#else
    return exp2f(x);
#endif
}
__device__ __forceinline__ float fast_tanh(float x) {   // out_final only
    return 1.0f - 2.0f * __builtin_amdgcn_rcpf(1.0f + exp2_hw(SN * x));
}
__device__ __forceinline__ f32x4 mfma16f(f16x8 a, f16x8 b, f32x4 c) {
    return __builtin_amdgcn_mfma_f32_16x16x32_f16(a, b, c, 0, 0, 0);
}

union PU { fp16x2 h2[4]; f16x8 v; };
union GU { uint2 u; _Float16 h[4]; };

__device__ __forceinline__ f16x8 pack_f16(float4 a, float4 b) {
    PU u;
    u.h2[0] = __builtin_amdgcn_cvt_pkrtz(a.x, a.y);
    u.h2[1] = __builtin_amdgcn_cvt_pkrtz(a.z, a.w);
    u.h2[2] = __builtin_amdgcn_cvt_pkrtz(b.x, b.y);
    u.h2[3] = __builtin_amdgcn_cvt_pkrtz(b.z, b.w);
    return u.v;
}

// Raw barrier: drain LDS only. Global loads/stores (vmcnt) stay in flight.
__device__ __forceinline__ void wg_barrier() {
    __builtin_amdgcn_sched_barrier(0);
    asm volatile("s_waitcnt lgkmcnt(0)" ::: "memory");
    __builtin_amdgcn_s_barrier();
    asm volatile("" ::: "memory");
    __builtin_amdgcn_sched_barrier(0);
}

// prescaled gates: a0,a1 already *SR; a2,a3 already *SN
__device__ __forceinline__ void gates(float a0v, float a1v, float a2v, float a3v,
                                      float& h_old, float wout, float& psum,
                                      _Float16& h16) {
    float r = __builtin_amdgcn_rcpf(1.0f + exp2_hw(-a0v));
    float z = __builtin_amdgcn_rcpf(1.0f + exp2_hw(-a1v));
    float y = fmaf(r, a3v, a2v);
    float n = fmaf(-2.0f, __builtin_amdgcn_rcpf(1.0f + exp2_hw(y)), 1.0f);
    float hn = fmaf(z, h_old - n, n);
    h_old = hn;
    h16 = (_Float16)hn;
    psum = fmaf(wout, hn, psum);
}

// ---------------- pre-GEMM: gi (fp16, prescaled, biases folded) -----------
// gi as uint2[TSEQ][96][NB]; x tile LDS-staged with coalesced loads.
__global__ __launch_bounds__(512)
void gi_gemm16(const float* __restrict__ x,
               const float* __restrict__ W_ih,
               const float* __restrict__ b_ih,
               const float* __restrict__ b_hh,
               uint2* __restrict__ gi)
{
    const int tid  = threadIdx.x;
    const int w    = tid >> 6;
    const int lane = tid & 63;
    const int g4   = lane >> 4;
    const int bcol = lane & 15;
    const int b0   = blockIdx.x * 16;
    const int t0   = blockIdx.y * 16;

    __shared__ __align__(16) _Float16 xt[16 * 1032 + 8];  // [b]: 1024 halves +8 pad

    // ---- stage x tile (coalesced 512B/instr) ----
    {
        const int bl = tid >> 5, q = tid & 31;
        const float* xp = x + ((size_t)(b0 + bl) * TSEQ + t0) * FDIM;
        _Float16* dst = &xt[bl * 1032];
        #pragma unroll
        for (int j = 0; j < 8; ++j) {
            float4 v = *(const float4*)(xp + j * 128 + q * 4);
            union { fp16x2 p[2]; uint2 u; } pu;
            pu.p[0] = __builtin_amdgcn_cvt_pkrtz(v.x, v.y);
            pu.p[1] = __builtin_amdgcn_cvt_pkrtz(v.z, v.w);
            *(uint2*)&dst[j * 128 + q * 4] = pu.u;
        }
    }

    f16x8 WihF[3][2];
    #pragma unroll
    for (int kd = 0; kd < 3; ++kd) {
        const float sc = (kd < 2) ? SR : SN;
        const int g = kd * 128 + w * 16 + bcol;
        #pragma unroll
        for (int kt = 0; kt < 2; ++kt) {
            const float* pw = W_ih + g * FDIM + kt * 32 + g4 * 8;
            f16x8 v;
            #pragma unroll
            for (int e = 0; e < 8; ++e) v[e] = (_Float16)(pw[e] * sc);
            WihF[kd][kt] = v;
        }
    }
    f32x4 biasR, biasZ, biasN;
    #pragma unroll
    for (int i = 0; i < 4; ++i) {
        const int gr = w * 16 + g4 * 4 + i;
        biasR[i] = (b_ih[gr]       + b_hh[gr])       * SR;
        biasZ[i] = (b_ih[128 + gr] + b_hh[128 + gr]) * SR;
        biasN[i] = b_ih[256 + gr] * SN;
    }
    __syncthreads();

    for (int tt = 0; tt < 16; ++tt) {
        const _Float16* xr = &xt[bcol * 1032 + tt * 64];
        f16x8 xf0 = *(const f16x8*)(xr + g4 * 8);
        f16x8 xf1 = *(const f16x8*)(xr + 32 + g4 * 8);

        f32x4 c0 = biasR, c1 = biasZ, c2 = biasN;
        c0 = mfma16f(WihF[0][0], xf0, c0);
        c0 = mfma16f(WihF[0][1], xf1, c0);
        c1 = mfma16f(WihF[1][0], xf0, c1);
        c1 = mfma16f(WihF[1][1], xf1, c1);
        c2 = mfma16f(WihF[2][0], xf0, c2);
        c2 = mfma16f(WihF[2][1], xf1, c2);

        GU g0, g1, g2;
        #pragma unroll
        for (int i = 0; i < 4; ++i) {
            g0.h[i] = (_Float16)c0[i];
            g1.h[i] = (_Float16)c1[i];
            g2.h[i] = (_Float16)c2[i];
        }
        const int t = t0 + tt;
        const size_t base = ((size_t)t * 96 + w * 4 + g4) * NB + (b0 + bcol);
        gi[base]           = g0.u;
        gi[base + 32 * NB] = g1.u;
        gi[base + 64 * NB] = g2.u;
    }
}

// ---------------- out finalize: out[b][t] = tanh(sum(pp) + b_out) ---------
__global__ __launch_bounds__(512)
void out_final(const float* __restrict__ pp,
               const float* __restrict__ b_out,
               float* __restrict__ out)
{
    const int t = blockIdx.x;
    const int b = threadIdx.x;
    float acc = b_out[0];
    const float* p = pp + (size_t)t * 32 * NB + b;
    #pragma unroll
    for (int c = 0; c < 32; ++c) acc += p[(size_t)c * NB];
    out[(size_t)b * TSEQ + t] = fast_tanh(acc);
}

// ---------------- recurrence ----------------------------------------------
// 32 blocks x 16 batches, 8 waves. fp16 single-term, f32 acc, prescaled.
// USE_GI: 12 h-MFMA/wave/step, gi 4-slot prefetch; per-lane psum partials
// stored fire-and-forget to pp (no shfl, no wave-0 straggler, no ps_s).
// !USE_GI: R9-proven in-loop x path with in-loop psum/out.
template<bool USE_GI>
__global__ __launch_bounds__(512, 2)
void gru_f16(const float* __restrict__ x,
             const float* __restrict__ W_ih,
             const float* __restrict__ W_hh,
             const float* __restrict__ b_ih,
             const float* __restrict__ b_hh,
             const float* __restrict__ W_out,
             const float* __restrict__ b_out,
             const uint2* __restrict__ gi,
             float* __restrict__ pp,
             float* __restrict__ out)
{
    const int tid  = threadIdx.x;
    const int wid  = tid >> 6;
    const int lane = tid & 63;
    const int g4   = lane >> 4;
    const int bcol = lane & 15;
    const int b0   = blockIdx.x * 16;

    __shared__ __align__(16) _Float16 h_s[3][16][H_ROW];
    __shared__ __align__(16) float ps_s[3][16][12];   // fallback only

    f16x8 WhhF[3][4];
    f16x8 WihF[3][2];
    #pragma unroll
    for (int kd = 0; kd < 3; ++kd) {
        const float sc = (kd < 2) ? SR : SN;
        const int g = kd * 128 + wid * 16 + bcol;
        #pragma unroll
        for (int kt = 0; kt < 4; ++kt) {
            const float* pw = W_hh + g * HDIM + kt * 32 + g4 * 8;
            f16x8 v;
            #pragma unroll
            for (int e = 0; e < 8; ++e) v[e] = (_Float16)(pw[e] * sc);
            WhhF[kd][kt] = v;
        }
        if constexpr (!USE_GI) {
            #pragma unroll
            for (int kt = 0; kt < 2; ++kt) {
                const float* pw = W_ih + g * FDIM + kt * 32 + g4 * 8;
                f16x8 v;
                #pragma unroll
                for (int e = 0; e < 8; ++e) v[e] = (_Float16)(pw[e] * sc);
                WihF[kd][kt] = v;
            }
        }
    }

    f32x4 biasR, biasZ, biasNI, biasNH;
    float wout_r[4], h_old[4];
    #pragma unroll
    for (int i = 0; i < 4; ++i) {
        const int gr = wid * 16 + g4 * 4 + i;
        if constexpr (!USE_GI) {
            biasR[i]  = (b_ih[gr]       + b_hh[gr])       * SR;
            biasZ[i]  = (b_ih[128 + gr] + b_hh[128 + gr]) * SR;
            biasNI[i] = b_ih[256 + gr] * SN;
        }
        biasNH[i] = b_hh[256 + gr] * SN;
        wout_r[i] = W_out[gr];
        h_old[i]  = 0.0f;
    }
    const float bout = b_out[0];

    {   // zero h buffer 0
        unsigned* hp = (unsigned*)&h_s[0][0][0];
        for (int i = tid; i < H_BUF / 2; i += 512) hp[i] = 0u;
    }

    // ---- input pipelines ----
    const float* xb = x + (size_t)(b0 + bcol) * TSEQ * FDIM;
    float4 sA0, sA1, sA2, sA3, sB0, sB1, sB2, sB3;
    f16x8 xf0, xf1;
    GU r0s, z0s, n0s, r1s, z1s, n1s, r2s, z2s, n2s, r3s, z3s, n3s;
    const uint2* gB = nullptr;
    float* ppp = nullptr;

    if constexpr (USE_GI) {
        gB  = gi + ((size_t)wid * 4 + g4) * NB + (b0 + bcol);
        ppp = pp + ((size_t)wid * 4 + g4) * NB + (b0 + bcol);
        r0s.u = gB[0];                              z0s.u = gB[32 * NB];
        n0s.u = gB[64 * NB];
        r1s.u = gB[(size_t)96 * NB];                z1s.u = gB[(size_t)96 * NB + 32 * NB];
        n1s.u = gB[(size_t)96 * NB + 64 * NB];
        r2s.u = gB[(size_t)192 * NB];               z2s.u = gB[(size_t)192 * NB + 32 * NB];
        n2s.u = gB[(size_t)192 * NB + 64 * NB];
        r3s.u = gB[(size_t)288 * NB];               z3s.u = gB[(size_t)288 * NB + 32 * NB];
        n3s.u = gB[(size_t)288 * NB + 64 * NB];
    } else {
        sA0 = *(const float4*)(xb + g4 * 8);
        sA1 = *(const float4*)(xb + g4 * 8 + 4);
        sA2 = *(const float4*)(xb + 32 + g4 * 8);
        sA3 = *(const float4*)(xb + 32 + g4 * 8 + 4);
        const float* xp1 = xb + FDIM;
        sB0 = *(const float4*)(xp1 + g4 * 8);
        sB1 = *(const float4*)(xp1 + g4 * 8 + 4);
        sB2 = *(const float4*)(xp1 + 32 + g4 * 8);
        sB3 = *(const float4*)(xp1 + 32 + g4 * 8 + 4);
        xf0 = pack_f16(sA0, sA1);
        xf1 = pack_f16(sA2, sA3);
    }

    __syncthreads();   // prologue barrier

    const bool outw = (!USE_GI) && (wid == 0) && (lane < 16);
    float* outp = out + (size_t)(b0 + lane) * TSEQ;
    float o0 = 0.f, o1 = 0.f, o2 = 0.f, o3 = 0.f;
    int rb = 0, wb = 1;

#define GI_STEP(RS, ZS, NS)                                                 \
    a0 = (f32x4){(float)RS.h[0], (float)RS.h[1],                            \
                 (float)RS.h[2], (float)RS.h[3]};                           \
    a1 = (f32x4){(float)ZS.h[0], (float)ZS.h[1],                            \
                 (float)ZS.h[2], (float)ZS.h[3]};                           \
    a2 = (f32x4){(float)NS.h[0], (float)NS.h[1],                            \
                 (float)NS.h[2], (float)NS.h[3]};                           \
    if (s + 4 < TSEQ) {                                                     \
        const size_t gof = (size_t)(s + 4) * 96 * NB;                       \
        RS.u = gB[gof];                                                     \
        ZS.u = gB[gof + 32 * NB];                                           \
        NS.u = gB[gof + 64 * NB];                                           \
    }

    for (int t = 0; t < TSEQ; t += 4) {
        #pragma unroll
        for (int u = 0; u < 4; ++u) {
            const int s = t + u;

            if (outw && s > 0) {
                f32x4 q0 = *(const f32x4*)&ps_s[rb][lane][0];
                f32x4 q1 = *(const f32x4*)&ps_s[rb][lane][4];
                float sm = (q0[0] + q0[1]) + (q0[2] + q0[3])
                         + (q1[0] + q1[1]) + (q1[2] + q1[3]);
                float val = fast_tanh(sm + bout);
                if (u == 0) {
                    o3 = val;
                    *(float4*)(outp + (t - 4)) = make_float4(o0, o1, o2, o3);
                } else if (u == 1) o0 = val;
                else if (u == 2) o1 = val;
                else o2 = val;
            }

            f32x4 a0, a1, a2, a3;

            f16x8 bh0 = *(const f16x8*)&h_s[rb][bcol][0 * 32 + g4 * 8];
            f16x8 bh1 = *(const f16x8*)&h_s[rb][bcol][1 * 32 + g4 * 8];
            f16x8 bh2 = *(const f16x8*)&h_s[rb][bcol][2 * 32 + g4 * 8];
            f16x8 bh3 = *(const f16x8*)&h_s[rb][bcol][3 * 32 + g4 * 8];

            if constexpr (USE_GI) {
                if (u == 0)      { GI_STEP(r0s, z0s, n0s) }
                else if (u == 1) { GI_STEP(r1s, z1s, n1s) }
                else if (u == 2) { GI_STEP(r2s, z2s, n2s) }
                else             { GI_STEP(r3s, z3s, n3s) }
                a3 = biasNH;

                a0 = mfma16f(WhhF[0][0], bh0, a0);
                a1 = mfma16f(WhhF[1][0], bh0, a1);
                a3 = mfma16f(WhhF[2][0], bh0, a3);
                a0 = mfma16f(WhhF[0][1], bh1, a0);
                a1 = mfma16f(WhhF[1][1], bh1, a1);
                a3 = mfma16f(WhhF[2][1], bh1, a3);
                a0 = mfma16f(WhhF[0][2], bh2, a0);
                a1 = mfma16f(WhhF[1][2], bh2, a1);
                a3 = mfma16f(WhhF[2][2], bh2, a3);
                a0 = mfma16f(WhhF[0][3], bh3, a0);
                a1 = mfma16f(WhhF[1][3], bh3, a1);
                a3 = mfma16f(WhhF[2][3], bh3, a3);
            } else {
                {
                    const int tl = (s + 2 < TSEQ) ? (s + 2) : (TSEQ - 1);
                    const float* xp = xb + (size_t)tl * FDIM;
                    if ((u & 1) == 0) {
                        sA0 = *(const float4*)(xp + g4 * 8);
                        sA1 = *(const float4*)(xp + g4 * 8 + 4);
                        sA2 = *(const float4*)(xp + 32 + g4 * 8);
                        sA3 = *(const float4*)(xp + 32 + g4 * 8 + 4);
                    } else {
                        sB0 = *(const float4*)(xp + g4 * 8);
                        sB1 = *(const float4*)(xp + g4 * 8 + 4);
                        sB2 = *(const float4*)(xp + 32 + g4 * 8);
                        sB3 = *(const float4*)(xp + 32 + g4 * 8 + 4);
                    }
                }
                a0 = biasR; a1 = biasZ; a2 = biasNI; a3 = biasNH;
                a0 = mfma16f(WihF[0][0], xf0, a0);
                a0 = mfma16f(WihF[0][1], xf1, a0);
                a1 = mfma16f(WihF[1][0], xf0, a1);
                a1 = mfma16f(WihF[1][1], xf1, a1);
                a2 = mfma16f(WihF[2][0], xf0, a2);
                a2 = mfma16f(WihF[2][1], xf1, a2);

                a0 = mfma16f(WhhF[0][0], bh0, a0);
                a1 = mfma16f(WhhF[1][0], bh0, a1);
                a3 = mfma16f(WhhF[2][0], bh0, a3);
                a0 = mfma16f(WhhF[0][1], bh1, a0);
                a1 = mfma16f(WhhF[1][1], bh1, a1);
                a3 = mfma16f(WhhF[2][1], bh1, a3);
                a0 = mfma16f(WhhF[0][2], bh2, a0);
                a1 = mfma16f(WhhF[1][2], bh2, a1);
                a3 = mfma16f(WhhF[2][2], bh2, a3);
                a0 = mfma16f(WhhF[0][3], bh3, a0);
                a1 = mfma16f(WhhF[1][3], bh3, a1);
                a3 = mfma16f(WhhF[2][3], bh3, a3);
            }

            // ---- gates (prescaled, exp2-based) ----
            float psum = 0.0f;
            _Float16 h16[4];
            #pragma unroll
            for (int i = 0; i < 4; ++i)
                gates(a0[i], a1[i], a2[i], a3[i], h_old[i], wout_r[i],
                      psum, h16[i]);

            union { _Float16 h[4]; uint2 u; } hu;
            hu.h[0] = h16[0]; hu.h[1] = h16[1];
            hu.h[2] = h16[2]; hu.h[3] = h16[3];
            *(uint2*)&h_s[wb][bcol][wid * 16 + g4 * 4] = hu.u;

            if constexpr (USE_GI) {
                *ppp = psum;              // fire-and-forget partial
                ppp += 32 * NB;
            } else {
                psum += __shfl_xor(psum, 16);
                psum += __shfl_xor(psum, 32);
                if (lane < 16) ps_s[wb][lane][wid] = psum;
            }

            if constexpr (!USE_GI) {
                if ((u & 1) == 0) {
                    xf0 = pack_f16(sB0, sB1);
                    xf1 = pack_f16(sB2, sB3);
                } else {
                    xf0 = pack_f16(sA0, sA1);
                    xf1 = pack_f16(sA2, sA3);
                }
            }

            wg_barrier();
            rb = wb; wb = (wb == 2) ? 0 : wb + 1;
        }
    }
#undef GI_STEP

    if (outw) {
        f32x4 q0 = *(const f32x4*)&ps_s[2][lane][0];
        f32x4 q1 = *(const f32x4*)&ps_s[2][lane][4];
        float sm = (q0[0] + q0[1]) + (q0[2] + q0[3])
                 + (q1[0] + q1[1]) + (q1[2] + q1[3]);
        o3 = fast_tanh(sm + bout);
        *(float4*)(outp + (TSEQ - 4)) = make_float4(o0, o1, o2, o3);
    }
}

extern "C" void kernel_launch(void* const* d_in, const int* in_sizes, int n_in,
                              void* d_out, int out_size, void* d_ws, size_t ws_size,
                              hipStream_t stream) {
    const float* x     = (const float*)d_in[0];
    const float* W_ih  = (const float*)d_in[1];
    const float* W_hh  = (const float*)d_in[2];
    const float* b_ih  = (const float*)d_in[3];
    const float* b_hh  = (const float*)d_in[4];
    const float* W_out = (const float*)d_in[5];
    const float* b_out = (const float*)d_in[6];
    float* out = (float*)d_out;

    const size_t gi_bytes = (size_t)TSEQ * NB * 384 * sizeof(_Float16); // 201.3 MB
    const size_t pp_bytes = (size_t)TSEQ * 32 * NB * sizeof(float);     // 33.6 MB

    if (ws_size >= gi_bytes + pp_bytes) {
        uint2* gi = (uint2*)d_ws;
        float* pp = (float*)((char*)d_ws + gi_bytes);
        gi_gemm16<<<dim3(32, 32), 512, 0, stream>>>(x, W_ih, b_ih, b_hh, gi);
        gru_f16<true><<<32, 512, 0, stream>>>(x, W_ih, W_hh, b_ih, b_hh,
                                              W_out, b_out, gi, pp, out);
        out_final<<<TSEQ, NB, 0, stream>>>(pp, b_out, out);
    } else {
        gru_f16<false><<<32, 512, 0, stream>>>(x, W_ih, W_hh, b_ih, b_hh,
                                               W_out, b_out, nullptr, nullptr, out);
    }
}

// Round 13
// 344.997 us; speedup vs baseline: 1.5508x; 1.0566x over previous
//
#include <hip/hip_runtime.h>
#include <math.h>

#define TSEQ 512
#define FDIM 64
#define HDIM 128
#define NB   512

// prescales folded into weights/biases so activations use raw exp2
#define SR 1.4426950408889634f   // log2(e)   : r,z gates
#define SN 2.8853900817779268f   // 2*log2(e) : n gate

typedef _Float16 f16x8 __attribute__((ext_vector_type(8)));
typedef _Float16 f16x4 __attribute__((ext_vector_type(4)));
typedef __fp16  fp16x2 __attribute__((ext_vector_type(2)));
typedef __attribute__((ext_vector_type(4))) float f32x4;

#define H_ROW 136                 // halves per batch row (+8 pad)
#define H_BUF (16 * H_ROW)

#if __has_builtin(__builtin_amdgcn_mfma_f32_16x16x16f16)
#define HAVE_MFMA16K16 1
__device__ __forceinline__ f32x4 mfma16k16(f16x4 a, f16x4 b, f32x4 c) {
    return __builtin_amdgcn_mfma_f32_16x16x16f16(a, b, c, 0, 0, 0);
}
#elif __has_builtin(__builtin_amdgcn_mfma_f32_16x16x16_f16)
#define HAVE_MFMA16K16 1
__device__ __forceinline__ f32x4 mfma16k16(f16x4 a, f16x4 b, f32x4 c) {
    return __builtin_amdgcn_mfma_f32_16x16x16_f16(a, b, c, 0, 0, 0);
}
#else
#define HAVE_MFMA16K16 0
#endif

__device__ __forceinline__ float exp2_hw(float x) {
#if __has_builtin(__builtin_amdgcn_exp2f)
    return __builtin_amdgcn_exp2f(x);
#else
    return exp2f(x);
#endif
}
__device__ __forceinline__ float fast_tanh(float x) {   // out_final only
    return 1.0f - 2.0f * __builtin_amdgcn_rcpf(1.0f + exp2_hw(SN * x));
}
__device__ __forceinline__ f32x4 mfma16f(f16x8 a, f16x8 b, f32x4 c) {
    return __builtin_amdgcn_mfma_f32_16x16x32_f16(a, b, c, 0, 0, 0);
}

union PU { fp16x2 h2[4]; f16x8 v; };
union GU { uint2 u; _Float16 h[4]; f16x4 v; };

__device__ __forceinline__ f16x8 pack_f16(float4 a, float4 b) {
    PU u;
    u.h2[0] = __builtin_amdgcn_cvt_pkrtz(a.x, a.y);
    u.h2[1] = __builtin_amdgcn_cvt_pkrtz(a.z, a.w);
    u.h2[2] = __builtin_amdgcn_cvt_pkrtz(b.x, b.y);
    u.h2[3] = __builtin_amdgcn_cvt_pkrtz(b.z, b.w);
    return u.v;
}

// Raw barrier: drain LDS only. Global loads/stores (vmcnt) stay in flight.
__device__ __forceinline__ void wg_barrier() {
    __builtin_amdgcn_sched_barrier(0);
    asm volatile("s_waitcnt lgkmcnt(0)" ::: "memory");
    __builtin_amdgcn_s_barrier();
    asm volatile("" ::: "memory");
    __builtin_amdgcn_sched_barrier(0);
}

// prescaled gates: a0,a1 already *SR; a2,a3 already *SN
__device__ __forceinline__ void gates(float a0v, float a1v, float a2v, float a3v,
                                      float& h_old, float wout, float& psum,
                                      _Float16& h16) {
    float r = __builtin_amdgcn_rcpf(1.0f + exp2_hw(-a0v));
    float z = __builtin_amdgcn_rcpf(1.0f + exp2_hw(-a1v));
    float y = fmaf(r, a3v, a2v);
    float n = fmaf(-2.0f, __builtin_amdgcn_rcpf(1.0f + exp2_hw(y)), 1.0f);
    float hn = fmaf(z, h_old - n, n);
    h_old = hn;
    h16 = (_Float16)hn;
    psum = fmaf(wout, hn, psum);
}

// ---------------- pre-GEMM: gi (fp16, prescaled, biases folded) -----------
// gi as uint2[TSEQ][96][NB]; x tile LDS-staged with coalesced loads.
__global__ __launch_bounds__(512)
void gi_gemm16(const float* __restrict__ x,
               const float* __restrict__ W_ih,
               const float* __restrict__ b_ih,
               const float* __restrict__ b_hh,
               uint2* __restrict__ gi)
{
    const int tid  = threadIdx.x;
    const int w    = tid >> 6;
    const int lane = tid & 63;
    const int g4   = lane >> 4;
    const int bcol = lane & 15;
    const int b0   = blockIdx.x * 16;
    const int t0   = blockIdx.y * 16;

    __shared__ __align__(16) _Float16 xt[16 * 1032 + 8];

    {
        const int bl = tid >> 5, q = tid & 31;
        const float* xp = x + ((size_t)(b0 + bl) * TSEQ + t0) * FDIM;
        _Float16* dst = &xt[bl * 1032];
        #pragma unroll
        for (int j = 0; j < 8; ++j) {
            float4 v = *(const float4*)(xp + j * 128 + q * 4);
            union { fp16x2 p[2]; uint2 u; } pu;
            pu.p[0] = __builtin_amdgcn_cvt_pkrtz(v.x, v.y);
            pu.p[1] = __builtin_amdgcn_cvt_pkrtz(v.z, v.w);
            *(uint2*)&dst[j * 128 + q * 4] = pu.u;
        }
    }

    f16x8 WihF[3][2];
    #pragma unroll
    for (int kd = 0; kd < 3; ++kd) {
        const float sc = (kd < 2) ? SR : SN;
        const int g = kd * 128 + w * 16 + bcol;
        #pragma unroll
        for (int kt = 0; kt < 2; ++kt) {
            const float* pw = W_ih + g * FDIM + kt * 32 + g4 * 8;
            f16x8 v;
            #pragma unroll
            for (int e = 0; e < 8; ++e) v[e] = (_Float16)(pw[e] * sc);
            WihF[kd][kt] = v;
        }
    }
    f32x4 biasR, biasZ, biasN;
    #pragma unroll
    for (int i = 0; i < 4; ++i) {
        const int gr = w * 16 + g4 * 4 + i;
        biasR[i] = (b_ih[gr]       + b_hh[gr])       * SR;
        biasZ[i] = (b_ih[128 + gr] + b_hh[128 + gr]) * SR;
        biasN[i] = b_ih[256 + gr] * SN;
    }
    __syncthreads();

    for (int tt = 0; tt < 16; ++tt) {
        const _Float16* xr = &xt[bcol * 1032 + tt * 64];
        f16x8 xf0 = *(const f16x8*)(xr + g4 * 8);
        f16x8 xf1 = *(const f16x8*)(xr + 32 + g4 * 8);

        f32x4 c0 = biasR, c1 = biasZ, c2 = biasN;
        c0 = mfma16f(WihF[0][0], xf0, c0);
        c0 = mfma16f(WihF[0][1], xf1, c0);
        c1 = mfma16f(WihF[1][0], xf0, c1);
        c1 = mfma16f(WihF[1][1], xf1, c1);
        c2 = mfma16f(WihF[2][0], xf0, c2);
        c2 = mfma16f(WihF[2][1], xf1, c2);

        GU g0, g1, g2;
        #pragma unroll
        for (int i = 0; i < 4; ++i) {
            g0.h[i] = (_Float16)c0[i];
            g1.h[i] = (_Float16)c1[i];
            g2.h[i] = (_Float16)c2[i];
        }
        const int t = t0 + tt;
        const size_t base = ((size_t)t * 96 + w * 4 + g4) * NB + (b0 + bcol);
        gi[base]           = g0.u;
        gi[base + 32 * NB] = g1.u;
        gi[base + 64 * NB] = g2.u;
    }
}

// ---------------- out finalize: out[b][t] = tanh(sum(pp) + b_out) ---------
__global__ __launch_bounds__(512)
void out_final(const float* __restrict__ pp,
               const float* __restrict__ b_out,
               float* __restrict__ out)
{
    const int t = blockIdx.x;
    const int b = threadIdx.x;
    float acc = b_out[0];
    const float* p = pp + (size_t)t * 32 * NB + b;
    #pragma unroll
    for (int c = 0; c < 32; ++c) acc += p[(size_t)c * NB];
    out[(size_t)b * TSEQ + t] = fast_tanh(acc);
}

// ---------------- recurrence ----------------------------------------------
// 32 blocks x 16 batches, 8 waves. fp16 single-term, f32 acc, prescaled.
// USE_GI: gi injected into accumulators via identity-MFMA (A=I fragment,
// B=gi uint2-as-f16x4) -- replaces 12 scalar cvt + unpacks with 3 MFMAs
// that issue before the h ds_read lgkm wait. psum partials fire-and-forget
// to pp. !USE_GI: R9-proven in-loop x path.
template<bool USE_GI>
__global__ __launch_bounds__(512, 2)
void gru_f16(const float* __restrict__ x,
             const float* __restrict__ W_ih,
             const float* __restrict__ W_hh,
             const float* __restrict__ b_ih,
             const float* __restrict__ b_hh,
             const float* __restrict__ W_out,
             const float* __restrict__ b_out,
             const uint2* __restrict__ gi,
             float* __restrict__ pp,
             float* __restrict__ out)
{
    const int tid  = threadIdx.x;
    const int wid  = tid >> 6;
    const int lane = tid & 63;
    const int g4   = lane >> 4;
    const int bcol = lane & 15;
    const int b0   = blockIdx.x * 16;

    __shared__ __align__(16) _Float16 h_s[3][16][H_ROW];
    __shared__ __align__(16) float ps_s[3][16][12];   // fallback only

    f16x8 WhhF[3][4];
    f16x8 WihF[3][2];
    #pragma unroll
    for (int kd = 0; kd < 3; ++kd) {
        const float sc = (kd < 2) ? SR : SN;
        const int g = kd * 128 + wid * 16 + bcol;
        #pragma unroll
        for (int kt = 0; kt < 4; ++kt) {
            const float* pw = W_hh + g * HDIM + kt * 32 + g4 * 8;
            f16x8 v;
            #pragma unroll
            for (int e = 0; e < 8; ++e) v[e] = (_Float16)(pw[e] * sc);
            WhhF[kd][kt] = v;
        }
        if constexpr (!USE_GI) {
            #pragma unroll
            for (int kt = 0; kt < 2; ++kt) {
                const float* pw = W_ih + g * FDIM + kt * 32 + g4 * 8;
                f16x8 v;
                #pragma unroll
                for (int e = 0; e < 8; ++e) v[e] = (_Float16)(pw[e] * sc);
                WihF[kd][kt] = v;
            }
        }
    }

    // identity A-fragment for 16x16x16: A[r][k] = (r==k)
    f16x4 iden;
    #pragma unroll
    for (int e = 0; e < 4; ++e)
        iden[e] = (bcol == g4 * 4 + e) ? (_Float16)1.0f : (_Float16)0.0f;
    const f32x4 zero4 = {0.f, 0.f, 0.f, 0.f};

    f32x4 biasR, biasZ, biasNI, biasNH;
    float wout_r[4], h_old[4];
    #pragma unroll
    for (int i = 0; i < 4; ++i) {
        const int gr = wid * 16 + g4 * 4 + i;
        if constexpr (!USE_GI) {
            biasR[i]  = (b_ih[gr]       + b_hh[gr])       * SR;
            biasZ[i]  = (b_ih[128 + gr] + b_hh[128 + gr]) * SR;
            biasNI[i] = b_ih[256 + gr] * SN;
        }
        biasNH[i] = b_hh[256 + gr] * SN;
        wout_r[i] = W_out[gr];
        h_old[i]  = 0.0f;
    }
    const float bout = b_out[0];

    {   // zero h buffer 0
        unsigned* hp = (unsigned*)&h_s[0][0][0];
        for (int i = tid; i < H_BUF / 2; i += 512) hp[i] = 0u;
    }

    // ---- input pipelines ----
    const float* xb = x + (size_t)(b0 + bcol) * TSEQ * FDIM;
    float4 sA0, sA1, sA2, sA3, sB0, sB1, sB2, sB3;
    f16x8 xf0, xf1;
    GU r0s, z0s, n0s, r1s, z1s, n1s, r2s, z2s, n2s, r3s, z3s, n3s;
    const uint2* gB = nullptr;
    float* ppp = nullptr;

    if constexpr (USE_GI) {
        gB  = gi + ((size_t)wid * 4 + g4) * NB + (b0 + bcol);
        ppp = pp + ((size_t)wid * 4 + g4) * NB + (b0 + bcol);
        r0s.u = gB[0];                              z0s.u = gB[32 * NB];
        n0s.u = gB[64 * NB];
        r1s.u = gB[(size_t)96 * NB];                z1s.u = gB[(size_t)96 * NB + 32 * NB];
        n1s.u = gB[(size_t)96 * NB + 64 * NB];
        r2s.u = gB[(size_t)192 * NB];               z2s.u = gB[(size_t)192 * NB + 32 * NB];
        n2s.u = gB[(size_t)192 * NB + 64 * NB];
        r3s.u = gB[(size_t)288 * NB];               z3s.u = gB[(size_t)288 * NB + 32 * NB];
        n3s.u = gB[(size_t)288 * NB + 64 * NB];
    } else {
        sA0 = *(const float4*)(xb + g4 * 8);
        sA1 = *(const float4*)(xb + g4 * 8 + 4);
        sA2 = *(const float4*)(xb + 32 + g4 * 8);
        sA3 = *(const float4*)(xb + 32 + g4 * 8 + 4);
        const float* xp1 = xb + FDIM;
        sB0 = *(const float4*)(xp1 + g4 * 8);
        sB1 = *(const float4*)(xp1 + g4 * 8 + 4);
        sB2 = *(const float4*)(xp1 + 32 + g4 * 8);
        sB3 = *(const float4*)(xp1 + 32 + g4 * 8 + 4);
        xf0 = pack_f16(sA0, sA1);
        xf1 = pack_f16(sA2, sA3);
    }

    __syncthreads();   // prologue barrier

    const bool outw = (!USE_GI) && (wid == 0) && (lane < 16);
    float* outp = out + (size_t)(b0 + lane) * TSEQ;
    float o0 = 0.f, o1 = 0.f, o2 = 0.f, o3 = 0.f;
    int rb = 0, wb = 1;

#if HAVE_MFMA16K16
#define GI_INJECT(RS, ZS, NS)                                               \
    a0 = mfma16k16(iden, RS.v, zero4);                                      \
    a1 = mfma16k16(iden, ZS.v, zero4);                                      \
    a2 = mfma16k16(iden, NS.v, zero4);
#else
#define GI_INJECT(RS, ZS, NS)                                               \
    a0 = (f32x4){(float)RS.h[0], (float)RS.h[1],                            \
                 (float)RS.h[2], (float)RS.h[3]};                           \
    a1 = (f32x4){(float)ZS.h[0], (float)ZS.h[1],                            \
                 (float)ZS.h[2], (float)ZS.h[3]};                           \
    a2 = (f32x4){(float)NS.h[0], (float)NS.h[1],                            \
                 (float)NS.h[2], (float)NS.h[3]};
#endif

#define GI_STEP(RS, ZS, NS)                                                 \
    GI_INJECT(RS, ZS, NS)                                                   \
    if (s + 4 < TSEQ) {                                                     \
        const size_t gof = (size_t)(s + 4) * 96 * NB;                       \
        RS.u = gB[gof];                                                     \
        ZS.u = gB[gof + 32 * NB];                                           \
        NS.u = gB[gof + 64 * NB];                                           \
    }

    for (int t = 0; t < TSEQ; t += 4) {
        #pragma unroll
        for (int u = 0; u < 4; ++u) {
            const int s = t + u;

            if (outw && s > 0) {
                f32x4 q0 = *(const f32x4*)&ps_s[rb][lane][0];
                f32x4 q1 = *(const f32x4*)&ps_s[rb][lane][4];
                float sm = (q0[0] + q0[1]) + (q0[2] + q0[3])
                         + (q1[0] + q1[1]) + (q1[2] + q1[3]);
                float val = fast_tanh(sm + bout);
                if (u == 0) {
                    o3 = val;
                    *(float4*)(outp + (t - 4)) = make_float4(o0, o1, o2, o3);
                } else if (u == 1) o0 = val;
                else if (u == 2) o1 = val;
                else o2 = val;
            }

            f32x4 a0, a1, a2, a3;

            f16x8 bh0 = *(const f16x8*)&h_s[rb][bcol][0 * 32 + g4 * 8];
            f16x8 bh1 = *(const f16x8*)&h_s[rb][bcol][1 * 32 + g4 * 8];
            f16x8 bh2 = *(const f16x8*)&h_s[rb][bcol][2 * 32 + g4 * 8];
            f16x8 bh3 = *(const f16x8*)&h_s[rb][bcol][3 * 32 + g4 * 8];

            if constexpr (USE_GI) {
                if (u == 0)      { GI_STEP(r0s, z0s, n0s) }
                else if (u == 1) { GI_STEP(r1s, z1s, n1s) }
                else if (u == 2) { GI_STEP(r2s, z2s, n2s) }
                else             { GI_STEP(r3s, z3s, n3s) }
                a3 = biasNH;

                a0 = mfma16f(WhhF[0][0], bh0, a0);
                a1 = mfma16f(WhhF[1][0], bh0, a1);
                a3 = mfma16f(WhhF[2][0], bh0, a3);
                a0 = mfma16f(WhhF[0][1], bh1, a0);
                a1 = mfma16f(WhhF[1][1], bh1, a1);
                a3 = mfma16f(WhhF[2][1], bh1, a3);
                a0 = mfma16f(WhhF[0][2], bh2, a0);
                a1 = mfma16f(WhhF[1][2], bh2, a1);
                a3 = mfma16f(WhhF[2][2], bh2, a3);
                a0 = mfma16f(WhhF[0][3], bh3, a0);
                a1 = mfma16f(WhhF[1][3], bh3, a1);
                a3 = mfma16f(WhhF[2][3], bh3, a3);
            } else {
                {
                    const int tl = (s + 2 < TSEQ) ? (s + 2) : (TSEQ - 1);
                    const float* xp = xb + (size_t)tl * FDIM;
                    if ((u & 1) == 0) {
                        sA0 = *(const float4*)(xp + g4 * 8);
                        sA1 = *(const float4*)(xp + g4 * 8 + 4);
                        sA2 = *(const float4*)(xp + 32 + g4 * 8);
                        sA3 = *(const float4*)(xp + 32 + g4 * 8 + 4);
                    } else {
                        sB0 = *(const float4*)(xp + g4 * 8);
                        sB1 = *(const float4*)(xp + g4 * 8 + 4);
                        sB2 = *(const float4*)(xp + 32 + g4 * 8);
                        sB3 = *(const float4*)(xp + 32 + g4 * 8 + 4);
                    }
                }
                a0 = biasR; a1 = biasZ; a2 = biasNI; a3 = biasNH;
                a0 = mfma16f(WihF[0][0], xf0, a0);
                a0 = mfma16f(WihF[0][1], xf1, a0);
                a1 = mfma16f(WihF[1][0], xf0, a1);
                a1 = mfma16f(WihF[1][1], xf1, a1);
                a2 = mfma16f(WihF[2][0], xf0, a2);
                a2 = mfma16f(WihF[2][1], xf1, a2);

                a0 = mfma16f(WhhF[0][0], bh0, a0);
                a1 = mfma16f(WhhF[1][0], bh0, a1);
                a3 = mfma16f(WhhF[2][0], bh0, a3);
                a0 = mfma16f(WhhF[0][1], bh1, a0);
                a1 = mfma16f(WhhF[1][1], bh1, a1);
                a3 = mfma16f(WhhF[2][1], bh1, a3);
                a0 = mfma16f(WhhF[0][2], bh2, a0);
                a1 = mfma16f(WhhF[1][2], bh2, a1);
                a3 = mfma16f(WhhF[2][2], bh2, a3);
                a0 = mfma16f(WhhF[0][3], bh3, a0);
                a1 = mfma16f(WhhF[1][3], bh3, a1);
                a3 = mfma16f(WhhF[2][3], bh3, a3);
            }

            // ---- gates (prescaled, exp2-based) ----
            float psum = 0.0f;
            _Float16 h16[4];
            #pragma unroll
            for (int i = 0; i < 4; ++i)
                gates(a0[i], a1[i], a2[i], a3[i], h_old[i], wout_r[i],
                      psum, h16[i]);

            union { _Float16 h[4]; uint2 u; } hu;
            hu.h[0] = h16[0]; hu.h[1] = h16[1];
            hu.h[2] = h16[2]; hu.h[3] = h16[3];
            *(uint2*)&h_s[wb][bcol][wid * 16 + g4 * 4] = hu.u;

            if constexpr (USE_GI) {
                *ppp = psum;              // fire-and-forget partial
                ppp += 32 * NB;
            } else {
                psum += __shfl_xor(psum, 16);
                psum += __shfl_xor(psum, 32);
                if (lane < 16) ps_s[wb][lane][wid] = psum;
            }

            if constexpr (!USE_GI) {
                if ((u & 1) == 0) {
                    xf0 = pack_f16(sB0, sB1);
                    xf1 = pack_f16(sB2, sB3);
                } else {
                    xf0 = pack_f16(sA0, sA1);
                    xf1 = pack_f16(sA2, sA3);
                }
            }

            wg_barrier();
            rb = wb; wb = (wb == 2) ? 0 : wb + 1;
        }
    }
#undef GI_STEP
#undef GI_INJECT

    if (outw) {
        f32x4 q0 = *(const f32x4*)&ps_s[2][lane][0];
        f32x4 q1 = *(const f32x4*)&ps_s[2][lane][4];
        float sm = (q0[0] + q0[1]) + (q0[2] + q0[3])
                 + (q1[0] + q1[1]) + (q1[2] + q1[3]);
        o3 = fast_tanh(sm + bout);
        *(float4*)(outp + (TSEQ - 4)) = make_float4(o0, o1, o2, o3);
    }
}

extern "C" void kernel_launch(void* const* d_in, const int* in_sizes, int n_in,
                              void* d_out, int out_size, void* d_ws, size_t ws_size,
                              hipStream_t stream) {
    const float* x     = (const float*)d_in[0];
    const float* W_ih  = (const float*)d_in[1];
    const float* W_hh  = (const float*)d_in[2];
    const float* b_ih  = (const float*)d_in[3];
    const float* b_hh  = (const float*)d_in[4];
    const float* W_out = (const float*)d_in[5];
    const float* b_out = (const float*)d_in[6];
    float* out = (float*)d_out;

    const size_t gi_bytes = (size_t)TSEQ * NB * 384 * sizeof(_Float16); // 201.3 MB
    const size_t pp_bytes = (size_t)TSEQ * 32 * NB * sizeof(float);     // 33.6 MB

    if (ws_size >= gi_bytes + pp_bytes) {
        uint2* gi = (uint2*)d_ws;
        float* pp = (float*)((char*)d_ws + gi_bytes);
        gi_gemm16<<<dim3(32, 32), 512, 0, stream>>>(x, W_ih, b_ih, b_hh, gi);
        gru_f16<true><<<32, 512, 0, stream>>>(x, W_ih, W_hh, b_ih, b_hh,
                                              W_out, b_out, gi, pp, out);
        out_final<<<TSEQ, NB, 0, stream>>>(pp, b_out, out);
    } else {
        gru_f16<false><<<32, 512, 0, stream>>>(x, W_ih, W_hh, b_ih, b_hh,
                                               W_out, b_out, nullptr, nullptr, out);
    }
}